// Round 1
// baseline (15272.577 us; speedup 1.0000x reference)
//
#include <hip/hip_runtime.h>

#define NTOK 4096
#define DIM 1024
#define NH 16
#define HSZ 64
#define NL 4
#define FFD 4096
#define VOC 32000
#define SEQ 1024
#define NB 4
#define LNEPS 1e-5f

// ---------- helpers ----------
__device__ inline unsigned fenc(float f){
  unsigned u = __float_as_uint(f);
  return (u & 0x80000000u) ? ~u : (u | 0x80000000u);
}
__device__ inline float fdec(unsigned e){
  return (e & 0x80000000u) ? __uint_as_float(e & 0x7fffffffu) : __uint_as_float(~e);
}
__device__ inline float waveSum(float v){
  #pragma unroll
  for (int o = 32; o > 0; o >>= 1) v += __shfl_down(v, o);
  return v;
}
__device__ inline float waveMax(float v){
  #pragma unroll
  for (int o = 32; o > 0; o >>= 1) v = fmaxf(v, __shfl_down(v, o));
  return v;
}
// 256-thread (4-wave) block reductions with broadcast
__device__ inline float blockSum(float v, float* red){
  __syncthreads();
  v = waveSum(v);
  if ((threadIdx.x & 63) == 0) red[threadIdx.x >> 6] = v;
  __syncthreads();
  return red[0] + red[1] + red[2] + red[3];
}
__device__ inline float blockMax(float v, float* red){
  __syncthreads();
  v = waveMax(v);
  if ((threadIdx.x & 63) == 0) red[threadIdx.x >> 6] = v;
  __syncthreads();
  return fmaxf(fmaxf(red[0], red[1]), fmaxf(red[2], red[3]));
}

// ---------- embedding ----------
__global__ __launch_bounds__(256) void embed_kernel(const int* __restrict__ idx,
    const float* __restrict__ tok, const float* __restrict__ pos, float* __restrict__ x){
  int row = blockIdx.x;                // b*SEQ + t
  int c = threadIdx.x * 4;
  int tk = idx[row];
  int t = row & (SEQ - 1);
  float4 a = *(const float4*)(tok + (size_t)tk * DIM + c);
  float4 p = *(const float4*)(pos + (size_t)t * DIM + c);
  a.x += p.x; a.y += p.y; a.z += p.z; a.w += p.w;
  *(float4*)(x + (size_t)row * DIM + c) = a;
}

// ---------- layernorm (one block per row, D=1024) ----------
__global__ __launch_bounds__(256) void ln_kernel(const float* __restrict__ x, float* __restrict__ out,
    const float* __restrict__ g, const float* __restrict__ bta){
  __shared__ float red[4];
  int row = blockIdx.x;
  int c = threadIdx.x * 4;
  float4 a = *(const float4*)(x + (size_t)row * DIM + c);
  float s = a.x + a.y + a.z + a.w;
  float q = a.x*a.x + a.y*a.y + a.z*a.z + a.w*a.w;
  float S = blockSum(s, red);
  float Q = blockSum(q, red);
  float mean = S * (1.0f / DIM);
  float var = Q * (1.0f / DIM) - mean * mean;
  float rstd = rsqrtf(var + LNEPS);
  float4 gg = *(const float4*)(g + c);
  float4 bb = *(const float4*)(bta + c);
  float4 o;
  o.x = (a.x - mean) * rstd * gg.x + bb.x;
  o.y = (a.y - mean) * rstd * gg.y + bb.y;
  o.z = (a.z - mean) * rstd * gg.z + bb.z;
  o.w = (a.w - mean) * rstd * gg.w + bb.w;
  *(float4*)(out + (size_t)row * DIM + c) = o;
}

// ---------- Wq/Wk/Wv [H,D,HS] -> [D, H*HS] ----------
__global__ __launch_bounds__(256) void transw_kernel(const float* __restrict__ W, float* __restrict__ out){
  int i = (blockIdx.x * 256 + threadIdx.x) * 4;   // output flat index, 1M total
  int d = i >> 10, c = i & 1023;
  int hh = c >> 6, s = c & 63;
  float4 v = *(const float4*)(W + (size_t)hh * (DIM * HSZ) + (size_t)d * HSZ + s);
  *(float4*)(out + i) = v;
}

// ---------- generic fp32 GEMM, 64x64 tile, K-chunk 16, 256 threads ----------
// MODE 0: C = acc            MODE 2: C += acc + bias    MODE 3: C = relu(acc+bias)
// MODE 4: rowmax atomic      MODE 5: rowsum-exp atomic
template<int MODE>
__global__ __launch_bounds__(256) void gemm64(const float* __restrict__ A, const float* __restrict__ Bm,
    float* __restrict__ C, const float* __restrict__ bias,
    int K, int lda, int ldb, int ldc,
    unsigned* __restrict__ rowmax, float* __restrict__ rowsum){
  __shared__ float As[16][68];   // [k][m]
  __shared__ float Bs[16][68];   // [k][n]
  const int tid = threadIdx.x;
  const int tx = tid & 15, ty = tid >> 4;
  const int m0 = blockIdx.y * 64, n0 = blockIdx.x * 64;
  const int ar = tid >> 2, ak = (tid & 3) * 4;
  const int br = tid >> 4, bc = (tid & 15) * 4;
  float acc[4][4] = {};
  const float* Ap = A + (size_t)(m0 + ar) * lda + ak;
  const float* Bp = Bm + (size_t)br * ldb + n0 + bc;
  for (int k0 = 0; k0 < K; k0 += 16){
    float4 a = *(const float4*)(Ap + k0);
    float4 b = *(const float4*)(Bp + (size_t)k0 * ldb);
    __syncthreads();
    As[ak+0][ar] = a.x; As[ak+1][ar] = a.y; As[ak+2][ar] = a.z; As[ak+3][ar] = a.w;
    *(float4*)&Bs[br][bc] = b;
    __syncthreads();
    #pragma unroll
    for (int kk = 0; kk < 16; kk++){
      float4 av = *(const float4*)&As[kk][ty*4];
      float4 bv = *(const float4*)&Bs[kk][tx*4];
      float am[4] = {av.x, av.y, av.z, av.w};
      float bn[4] = {bv.x, bv.y, bv.z, bv.w};
      #pragma unroll
      for (int i = 0; i < 4; i++)
        #pragma unroll
        for (int j = 0; j < 4; j++)
          acc[i][j] = fmaf(am[i], bn[j], acc[i][j]);
    }
  }
  if (MODE == 0){
    #pragma unroll
    for (int i = 0; i < 4; i++){
      float4 r = make_float4(acc[i][0], acc[i][1], acc[i][2], acc[i][3]);
      *(float4*)(C + (size_t)(m0 + ty*4 + i) * ldc + n0 + tx*4) = r;
    }
  }
  if (MODE == 2){
    float4 bb = *(const float4*)(bias + n0 + tx*4);
    #pragma unroll
    for (int i = 0; i < 4; i++){
      float* cp = C + (size_t)(m0 + ty*4 + i) * ldc + n0 + tx*4;
      float4 c = *(float4*)cp;
      c.x += acc[i][0] + bb.x; c.y += acc[i][1] + bb.y;
      c.z += acc[i][2] + bb.z; c.w += acc[i][3] + bb.w;
      *(float4*)cp = c;
    }
  }
  if (MODE == 3){
    float4 bb = *(const float4*)(bias + n0 + tx*4);
    #pragma unroll
    for (int i = 0; i < 4; i++){
      float4 r;
      r.x = fmaxf(acc[i][0] + bb.x, 0.f); r.y = fmaxf(acc[i][1] + bb.y, 0.f);
      r.z = fmaxf(acc[i][2] + bb.z, 0.f); r.w = fmaxf(acc[i][3] + bb.w, 0.f);
      *(float4*)(C + (size_t)(m0 + ty*4 + i) * ldc + n0 + tx*4) = r;
    }
  }
  if (MODE == 4){
    float4 bb = *(const float4*)(bias + n0 + tx*4);
    __syncthreads();                       // done reading As -> reuse as scratch
    float (*red)[16] = reinterpret_cast<float(*)[16]>(&As[0][0]);
    #pragma unroll
    for (int i = 0; i < 4; i++){
      float m = fmaxf(fmaxf(acc[i][0] + bb.x, acc[i][1] + bb.y),
                      fmaxf(acc[i][2] + bb.z, acc[i][3] + bb.w));
      red[ty*4 + i][tx] = m;
    }
    __syncthreads();
    if (tid < 64){
      float m = red[tid][0];
      #pragma unroll
      for (int j = 1; j < 16; j++) m = fmaxf(m, red[tid][j]);
      atomicMax(&rowmax[m0 + tid], fenc(m));
    }
  }
  if (MODE == 5){
    float4 bb = *(const float4*)(bias + n0 + tx*4);
    __syncthreads();
    float (*red)[16] = reinterpret_cast<float(*)[16]>(&As[0][0]);
    #pragma unroll
    for (int i = 0; i < 4; i++){
      float mrow = fdec(rowmax[m0 + ty*4 + i]);
      float s = __expf(acc[i][0] + bb.x - mrow) + __expf(acc[i][1] + bb.y - mrow)
              + __expf(acc[i][2] + bb.z - mrow) + __expf(acc[i][3] + bb.w - mrow);
      red[ty*4 + i][tx] = s;
    }
    __syncthreads();
    if (tid < 64){
      float s = 0.f;
      #pragma unroll
      for (int j = 0; j < 16; j++) s += red[tid][j];
      atomicAdd(&rowsum[m0 + tid], s);
    }
  }
}

// ---------- attention raw scores: S = q k^T * scale (causal tiles only) ----------
__global__ __launch_bounds__(256) void scores_kernel(const float* __restrict__ q,
    const float* __restrict__ k, float* __restrict__ attnL){
  int kt = blockIdx.x, qt = blockIdx.y;
  if (kt > qt) return;
  int bh = blockIdx.z;
  int b = bh >> 4, h = bh & 15;
  __shared__ float qs[64][68];   // [s][t]
  __shared__ float ks[64][68];   // [s][j]
  int tid = threadIdx.x;
  int r = tid >> 2, s0 = (tid & 3) * 16;
  const float* qrow = q + (size_t)(b * SEQ + qt * 64 + r) * DIM + h * HSZ + s0;
  const float* krow = k + (size_t)(b * SEQ + kt * 64 + r) * DIM + h * HSZ + s0;
  #pragma unroll
  for (int u = 0; u < 16; u += 4){
    float4 a = *(const float4*)(qrow + u);
    float4 c = *(const float4*)(krow + u);
    qs[s0+u+0][r] = a.x; qs[s0+u+1][r] = a.y; qs[s0+u+2][r] = a.z; qs[s0+u+3][r] = a.w;
    ks[s0+u+0][r] = c.x; ks[s0+u+1][r] = c.y; ks[s0+u+2][r] = c.z; ks[s0+u+3][r] = c.w;
  }
  __syncthreads();
  int tx = tid & 15, ty = tid >> 4;
  float acc[4][4] = {};
  #pragma unroll 8
  for (int s = 0; s < 64; s++){
    float4 av = *(const float4*)&qs[s][ty*4];
    float4 bv = *(const float4*)&ks[s][tx*4];
    float am[4] = {av.x, av.y, av.z, av.w};
    float bn[4] = {bv.x, bv.y, bv.z, bv.w};
    #pragma unroll
    for (int i = 0; i < 4; i++)
      #pragma unroll
      for (int j = 0; j < 4; j++)
        acc[i][j] = fmaf(am[i], bn[j], acc[i][j]);
  }
  #pragma unroll
  for (int i = 0; i < 4; i++){
    int t = qt*64 + ty*4 + i;
    float* outp = attnL + ((size_t)bh * SEQ + t) * SEQ + kt*64 + tx*4;
    #pragma unroll
    for (int j = 0; j < 4; j++) outp[j] = acc[i][j] * 0.125f;   // scalar: attn base is +1 float
  }
}

// ---------- causal softmax per row, writes probs + zeros ----------
__global__ __launch_bounds__(256) void softmax_kernel(float* __restrict__ attnL){
  __shared__ float buf[SEQ];
  __shared__ float red[4];
  int row = blockIdx.x;                    // bh*SEQ + t
  int t = row & (SEQ - 1);
  float* p = attnL + (size_t)row * SEQ;
  int len = t + 1;
  int tid = threadIdx.x;
  float mx = -3.4e38f;
  for (int j = tid; j < len; j += 256){ float v = p[j]; buf[j] = v; mx = fmaxf(mx, v); }
  mx = blockMax(mx, red);
  float s = 0.f;
  for (int j = tid; j < len; j += 256){ float e = __expf(buf[j] - mx); buf[j] = e; s += e; }
  s = blockSum(s, red);
  float inv = 1.0f / s;
  for (int j = tid; j < len; j += 256) p[j] = buf[j] * inv;
  for (int j = len + tid; j < SEQ; j += 256) p[j] = 0.0f;
}

// ---------- O = P @ V, per (b,h), causal K-range ----------
__global__ __launch_bounds__(256) void pv_kernel(const float* __restrict__ attnL,
    const float* __restrict__ v, float* __restrict__ o){
  int qt = blockIdx.x, bh = blockIdx.y;
  int b = bh >> 4, h = bh & 15;
  __shared__ float Ps[16][68];
  __shared__ float Vs[16][68];
  int tid = threadIdx.x;
  int tx = tid & 15, ty = tid >> 4;
  int ar = tid >> 2, ak = (tid & 3) * 4;
  int br = tid >> 4, bc = (tid & 15) * 4;
  int m0 = qt * 64;
  const float* Prow = attnL + ((size_t)bh * SEQ + m0 + ar) * SEQ + ak;
  const float* Vbase = v + (size_t)b * SEQ * DIM + h * HSZ + bc;
  int kmax = (qt + 1) * 64;
  float acc[4][4] = {};
  for (int k0 = 0; k0 < kmax; k0 += 16){
    float a0 = Prow[k0], a1 = Prow[k0+1], a2 = Prow[k0+2], a3 = Prow[k0+3];  // scalar: misaligned base
    float4 bv = *(const float4*)(Vbase + (size_t)(k0 + br) * DIM);
    __syncthreads();
    Ps[ak+0][ar] = a0; Ps[ak+1][ar] = a1; Ps[ak+2][ar] = a2; Ps[ak+3][ar] = a3;
    *(float4*)&Vs[br][bc] = bv;
    __syncthreads();
    #pragma unroll
    for (int kk = 0; kk < 16; kk++){
      float4 av = *(const float4*)&Ps[kk][ty*4];
      float4 bw = *(const float4*)&Vs[kk][tx*4];
      float am[4] = {av.x, av.y, av.z, av.w};
      float bn[4] = {bw.x, bw.y, bw.z, bw.w};
      #pragma unroll
      for (int i = 0; i < 4; i++)
        #pragma unroll
        for (int j = 0; j < 4; j++)
          acc[i][j] = fmaf(am[i], bn[j], acc[i][j]);
    }
  }
  #pragma unroll
  for (int i = 0; i < 4; i++){
    float4 r = make_float4(acc[i][0], acc[i][1], acc[i][2], acc[i][3]);
    *(float4*)(o + (size_t)(b * SEQ + m0 + ty*4 + i) * DIM + h * HSZ + tx*4) = r;
  }
}

// ---------- LM-head stats init ----------
__global__ __launch_bounds__(256) void init_stats(unsigned* __restrict__ rowmax, float* __restrict__ rowsum){
  int i = blockIdx.x * 256 + threadIdx.x;
  if (i < NTOK){ rowmax[i] = 0u; rowsum[i] = 0.f; }
}

// ---------- target logit: dot(h[tok], Wlm[:,tgt]) + blm[tgt], one wave per token ----------
__global__ __launch_bounds__(256) void tgt_kernel(const float* __restrict__ hf,
    const float* __restrict__ Wlm, const float* __restrict__ blm,
    const int* __restrict__ tgt, float* __restrict__ out){
  int tok = blockIdx.x * 4 + (threadIdx.x >> 6);
  int lane = threadIdx.x & 63;
  int t = tgt[tok];
  const float* hr = hf + (size_t)tok * DIM;
  float s = 0.f;
  #pragma unroll
  for (int i = 0; i < 16; i++){
    int d = lane + i * 64;
    s = fmaf(hr[d], Wlm[(size_t)d * VOC + t], s);
  }
  s = waveSum(s);
  if (lane == 0) out[tok] = s + blm[t];
}

// ---------- final loss ----------
__global__ __launch_bounds__(256) void loss_kernel(const unsigned* __restrict__ rowmax,
    const float* __restrict__ rowsum, const float* __restrict__ tgtl, float* __restrict__ out){
  __shared__ float red[4];
  float s = 0.f;
  for (int i = threadIdx.x; i < NTOK; i += 256)
    s += fdec(rowmax[i]) + logf(rowsum[i]) - tgtl[i];
  s = blockSum(s, red);
  if (threadIdx.x == 0) out[0] = s / (float)NTOK;
}

// ---------- host ----------
extern "C" void kernel_launch(void* const* d_in, const int* in_sizes, int n_in,
                              void* d_out, int out_size, void* d_ws, size_t ws_size,
                              hipStream_t stream){
  const int*   idx     = (const int*)  d_in[0];
  const int*   targets = (const int*)  d_in[1];
  const float* tok_emb = (const float*)d_in[2];
  const float* pos_emb = (const float*)d_in[3];
  const float* ln1_g   = (const float*)d_in[4];
  const float* ln1_b   = (const float*)d_in[5];
  const float* Wq      = (const float*)d_in[6];
  const float* Wk      = (const float*)d_in[7];
  const float* Wv      = (const float*)d_in[8];
  const float* Wp      = (const float*)d_in[9];
  const float* bp      = (const float*)d_in[10];
  const float* ln2_g   = (const float*)d_in[11];
  const float* ln2_b   = (const float*)d_in[12];
  const float* W1      = (const float*)d_in[13];
  const float* b1      = (const float*)d_in[14];
  const float* W2      = (const float*)d_in[15];
  const float* b2      = (const float*)d_in[16];
  const float* lnf_g   = (const float*)d_in[17];
  const float* lnf_b   = (const float*)d_in[18];
  const float* Wlm     = (const float*)d_in[19];
  const float* blm     = (const float*)d_in[20];

  float* out = (float*)d_out;
  float* attn_base = out + 1;                 // attn [L,B,H,T,T] starts after loss scalar

  const size_t ND = (size_t)NTOK * DIM;       // 4,194,304 floats
  float* ws   = (float*)d_ws;
  float* x    = ws;
  float* hbuf = x + ND;
  float* qb   = hbuf + ND;
  float* kb   = qb + ND;
  float* vb   = kb + ND;
  float* ob   = vb + ND;
  float* ubuf = qb;                            // MLP intermediate aliases q..o (exactly 4*ND)
  float* wqt  = ob + ND;
  float* wkt  = wqt + (size_t)DIM * DIM;
  float* wvt  = wkt + (size_t)DIM * DIM;
  unsigned* rowmax = (unsigned*)(wvt + (size_t)DIM * DIM);
  float* rowsum = (float*)(rowmax + NTOK);
  float* tgtl   = rowsum + NTOK;

  embed_kernel<<<NTOK, 256, 0, stream>>>(idx, tok_emb, pos_emb, x);

  for (int l = 0; l < NL; l++){
    const size_t wOff  = (size_t)l * DIM * DIM;       // Wq/Wk/Wv/Wp per-layer (H*D*HS = D*D)
    const size_t w1Off = (size_t)l * DIM * FFD;
    ln_kernel<<<NTOK, 256, 0, stream>>>(x, hbuf, ln1_g + l*DIM, ln1_b + l*DIM);
    transw_kernel<<<1024, 256, 0, stream>>>(Wq + wOff, wqt);
    transw_kernel<<<1024, 256, 0, stream>>>(Wk + wOff, wkt);
    transw_kernel<<<1024, 256, 0, stream>>>(Wv + wOff, wvt);
    gemm64<0><<<dim3(16,64), 256, 0, stream>>>(hbuf, wqt, qb, nullptr, DIM, DIM, DIM, DIM, nullptr, nullptr);
    gemm64<0><<<dim3(16,64), 256, 0, stream>>>(hbuf, wkt, kb, nullptr, DIM, DIM, DIM, DIM, nullptr, nullptr);
    gemm64<0><<<dim3(16,64), 256, 0, stream>>>(hbuf, wvt, vb, nullptr, DIM, DIM, DIM, DIM, nullptr, nullptr);
    float* attnL = attn_base + (size_t)l * NB * NH * SEQ * SEQ;
    scores_kernel<<<dim3(16,16,NB*NH), 256, 0, stream>>>(qb, kb, attnL);
    softmax_kernel<<<NB*NH*SEQ, 256, 0, stream>>>(attnL);
    pv_kernel<<<dim3(16, NB*NH), 256, 0, stream>>>(attnL, vb, ob);
    gemm64<2><<<dim3(16,64), 256, 0, stream>>>(ob, Wp + wOff, x, bp + l*DIM, DIM, DIM, DIM, DIM, nullptr, nullptr);
    ln_kernel<<<NTOK, 256, 0, stream>>>(x, hbuf, ln2_g + l*DIM, ln2_b + l*DIM);
    gemm64<3><<<dim3(64,64), 256, 0, stream>>>(hbuf, W1 + w1Off, ubuf, b1 + l*FFD, DIM, DIM, FFD, FFD, nullptr, nullptr);
    gemm64<2><<<dim3(16,64), 256, 0, stream>>>(ubuf, W2 + w1Off, x, b2 + l*DIM, FFD, FFD, DIM, DIM, nullptr, nullptr);
  }

  ln_kernel<<<NTOK, 256, 0, stream>>>(x, hbuf, lnf_g, lnf_b);
  init_stats<<<16, 256, 0, stream>>>(rowmax, rowsum);
  gemm64<4><<<dim3(VOC/64, 64), 256, 0, stream>>>(hbuf, Wlm, nullptr, blm, DIM, DIM, VOC, 0, rowmax, nullptr);
  gemm64<5><<<dim3(VOC/64, 64), 256, 0, stream>>>(hbuf, Wlm, nullptr, blm, DIM, DIM, VOC, 0, rowmax, rowsum);
  tgt_kernel<<<NTOK/4, 256, 0, stream>>>(hbuf, Wlm, blm, targets, tgtl);
  loss_kernel<<<1, 256, 0, stream>>>(rowmax, rowsum, tgtl, out);
}